// Round 10
// baseline (186.736 us; speedup 1.0000x reference)
//
#include <hip/hip_runtime.h>

#define N_NODES 50000
#define N_EDGES 800000
#define D 128
#define NB 196                 // buckets: bucket = dst >> 8, 256 nodes each
#define CAPB 8192              // fixed slots per bucket (mean 4082, ~64 sigma)
#define P1_BLOCKS 256
#define EPB ((N_EDGES + P1_BLOCKS - 1) / P1_BLOCKS)  // 3125 edges/block
#define CAP 64                 // LDS staging slots per bucket in part1

typedef __attribute__((ext_vector_type(8))) short short8;
typedef __attribute__((ext_vector_type(4))) float f32x4;

// round-to-nearest-even f32 -> bf16 (as ushort)
__device__ __forceinline__ unsigned short f2bf(float f) {
    unsigned int u = __builtin_bit_cast(unsigned int, f);
    u += 0x7FFFu + ((u >> 16) & 1u);
    return (unsigned short)(u >> 16);
}
__device__ __forceinline__ float bf2f(unsigned short h) {
    unsigned int u = ((unsigned int)h) << 16;
    return __builtin_bit_cast(float, u);
}

// ---------------------------------------------------------------------------
// gcur[b] = b * CAPB   (fixed bucket bases; no hist/scan/memset needed)
__global__ void k_init(int* __restrict__ gcur) {
    const int t = threadIdx.x;
    if (t < NB) gcur[t] = t * CAPB;
}

// ---------------------------------------------------------------------------
// Blocks [0, P1_BLOCKS): partition edges into fixed-base buckets with LDS
// write-combining. pbuf code: (local_dst << 16) | src.
// Blocks [P1_BLOCKS, P1_BLOCKS+16): pack Wab = [Wc + Wc@Wt ; W0 - Wt] (256x128)
// into bf16 B-fragment order for 16x16x32 (independent of partitioning — runs
// concurrently). Block P1_BLOCKS+16: bv = bc + bc@Wt.
__global__ __launch_bounds__(256) void k_part1(const int* __restrict__ src,
                                               const int* __restrict__ dst,
                                               int* __restrict__ gcur,
                                               unsigned int* __restrict__ pbuf,
                                               const float* __restrict__ Wc,
                                               const float* __restrict__ W0,
                                               const float* __restrict__ Wt,
                                               const float* __restrict__ bc,
                                               unsigned short* __restrict__ Wp,
                                               float* __restrict__ bv) {
    __shared__ union SM {
        struct { unsigned int stage[NB][CAP + 1]; int scnt[NB]; } p;
        float sWt[D * D];
    } sm;
    const int t = threadIdx.x;

    if (blockIdx.x >= P1_BLOCKS) {  // ---- weight-pack path ----
        const int wb = blockIdx.x - P1_BLOCKS;  // 0..16
        for (int i = t * 4; i < D * D; i += 256 * 4)
            *(float4*)(sm.sWt + i) = *(const float4*)(Wt + i);
        __syncthreads();

        if (wb == 16) {
            if (t < D) {
                float acc = bc[t];
#pragma unroll 16
                for (int k = 0; k < D; ++k) acc += bc[k] * sm.sWt[k * D + t];
                bv[t] = acc;
            }
            return;
        }
        const int id = wb * 256 + t;  // 0..4095
        const int lane = id & 63;
        const int tile = (id >> 6) & 7;
        const int step = id >> 9;
        const int n = tile * 16 + (lane & 15);
        const int kbase = step * 32 + (lane >> 4) * 8;
        unsigned short v[8];
#pragma unroll
        for (int j = 0; j < 8; ++j) {
            const int k = kbase + j;
            float f;
            if (k < D) {
                f = Wc[k * D + n];
#pragma unroll 16
                for (int m = 0; m < D; ++m) f += Wc[k * D + m] * sm.sWt[m * D + n];
            } else {
                f = W0[(k - D) * D + n] - sm.sWt[(k - D) * D + n];
            }
            v[j] = f2bf(f);
        }
        *(uint4*)(Wp + (long)id * 8) = *(uint4*)v;
        return;
    }

    // ---- partition path ----
    for (int i = t; i < NB; i += 256) sm.p.scnt[i] = 0;
    __syncthreads();

    const long e0 = (long)blockIdx.x * EPB;
    const long e1 = (e0 + EPB < N_EDGES) ? e0 + EPB : N_EDGES;
    for (long e = e0 + t; e < e1; e += 256) {
        const int s = src[e];
        const int d = dst[e];
        const int b = d >> 8;
        const unsigned int p = ((unsigned int)(d & 255) << 16) | (unsigned int)s;
        const int slot = atomicAdd(&sm.p.scnt[b], 1);
        if (slot < CAP) {
            sm.p.stage[b][slot] = p;
        } else {  // spill (statistically ~never; correctness for any distribution)
            const int pos = atomicAdd(&gcur[b], 1);
            pbuf[pos] = p;
        }
    }
    __syncthreads();
    // cooperative drain: thread t drains bucket t in one contiguous burst
    if (t < NB) {
        const int n = (sm.p.scnt[t] < CAP) ? sm.p.scnt[t] : CAP;
        if (n > 0) {
            const int pos = atomicAdd(&gcur[t], n);
            for (int i = 0; i < n; ++i) pbuf[pos + i] = sm.p.stage[t][i];
        }
    }
}

// ---------------------------------------------------------------------------
// Per-bucket local CSR build (hist + scan in LDS, scatter into L2-local window)
// + fused xcast for this block's own 256 nodes (same-block dinv dependency):
//   xd[n] = bf16(dinv[n]*x[n]),  gx[n][128:256] = bf16(x[n])
__global__ __launch_bounds__(256) void k_part2(const unsigned int* __restrict__ pbuf,
                                               const int* __restrict__ gcur,
                                               int* __restrict__ row_start,
                                               int* __restrict__ cnt,
                                               float* __restrict__ dinv,
                                               int* __restrict__ esrc,
                                               const float* __restrict__ x,
                                               unsigned short* __restrict__ xd,
                                               unsigned short* __restrict__ gx) {
    __shared__ int lcnt[256];
    __shared__ int lcur[256];
    __shared__ int stmp[256];
    __shared__ float sdinv[256];
    const int b = blockIdx.x;
    const int t = threadIdx.x;
    const int base = b * CAPB;
    const int n = gcur[b] - base;

    lcnt[t] = 0;
    __syncthreads();
    for (int i = t; i < n; i += 256) atomicAdd(&lcnt[pbuf[base + i] >> 16], 1);
    __syncthreads();

    const int c = lcnt[t];
    stmp[t] = c;
    __syncthreads();
    for (int off = 1; off < 256; off <<= 1) {
        int u = (t >= off) ? stmp[t - off] : 0;
        __syncthreads();
        stmp[t] += u;
        __syncthreads();
    }
    const int ls = base + stmp[t] - c;  // exclusive, within bucket window
    lcur[t] = ls;
    const float di = rsqrtf((float)c + 1.0f);
    sdinv[t] = di;
    const int node = b * 256 + t;
    if (node < N_NODES) {
        row_start[node] = ls;
        cnt[node] = c;
        dinv[node] = di;
    }
    __syncthreads();

    for (int i = t; i < n; i += 256) {
        const unsigned int p = pbuf[base + i];
        const int pos = atomicAdd(&lcur[p >> 16], 1);
        esrc[pos] = (int)(p & 0xFFFFu);
    }

    // ---- fused xcast for this block's nodes (reads sdinv; esrc not needed) ----
    const int cc = t & 15;   // 8-float chunk id
    const int lr = t >> 4;   // node sub-index
    for (int it = 0; it < 16; ++it) {
        const int nl = it * 16 + lr;
        const int nd = b * 256 + nl;
        if (nd < N_NODES) {
            const float dv = sdinv[nl];
            const float4 a = ((const float4*)x)[(long)nd * 32 + cc * 2];
            const float4 bb = ((const float4*)x)[(long)nd * 32 + cc * 2 + 1];
            const float f[8] = {a.x, a.y, a.z, a.w, bb.x, bb.y, bb.z, bb.w};
            unsigned short vd[8], vb[8];
#pragma unroll
            for (int j = 0; j < 8; ++j) {
                vd[j] = f2bf(dv * f[j]);
                vb[j] = f2bf(f[j]);
            }
            *(uint4*)(xd + (long)nd * 128 + cc * 8) = *(uint4*)vd;
            *(uint4*)(gx + (long)nd * 256 + 128 + cc * 8) = *(uint4*)vb;
        }
    }
}

// ---------------------------------------------------------------------------
// Gather (bf16 rows): one 64-lane wave per node (4 nodes / block, 12500 blocks).
//   g[n] = dinv[n] * ( sum_e xd[src_e] + xd[n] )      (xd pre-scaled by dinv)
// Lane layout: c = lane&15 -> 8-elem chunk (16 B), s = lane>>4 -> edge slot 0..3.
// Unroll 4 per slot: 16 outstanding 16 B loads per wave.
__global__ __launch_bounds__(256) void k_gather(const unsigned short* __restrict__ xd,
                                                const int* __restrict__ row_start,
                                                const int* __restrict__ cnt,
                                                const int* __restrict__ esrc,
                                                const float* __restrict__ dinv,
                                                unsigned short* __restrict__ gx) {
    const int node = blockIdx.x * 4 + (threadIdx.x >> 6);
    const int lane = threadIdx.x & 63;
    const int c = lane & 15;
    const int s = lane >> 4;
    const int begin = row_start[node];
    const int end = begin + cnt[node];

    float acc[8] = {};
    int i = begin + s;
    for (; i + 12 < end; i += 16) {  // four edges in flight per slot
        const int a0 = esrc[i];
        const int a1 = esrc[i + 4];
        const int a2 = esrc[i + 8];
        const int a3 = esrc[i + 12];
        const short8 v0 = *(const short8*)(xd + (long)a0 * 128 + c * 8);
        const short8 v1 = *(const short8*)(xd + (long)a1 * 128 + c * 8);
        const short8 v2 = *(const short8*)(xd + (long)a2 * 128 + c * 8);
        const short8 v3 = *(const short8*)(xd + (long)a3 * 128 + c * 8);
#pragma unroll
        for (int j = 0; j < 8; ++j)
            acc[j] += (bf2f((unsigned short)v0[j]) + bf2f((unsigned short)v1[j])) +
                      (bf2f((unsigned short)v2[j]) + bf2f((unsigned short)v3[j]));
    }
    for (; i < end; i += 4) {
        const int a0 = esrc[i];
        const short8 v0 = *(const short8*)(xd + (long)a0 * 128 + c * 8);
#pragma unroll
        for (int j = 0; j < 8; ++j) acc[j] += bf2f((unsigned short)v0[j]);
    }

#pragma unroll
    for (int j = 0; j < 8; ++j) {
        acc[j] += __shfl_xor(acc[j], 16);
        acc[j] += __shfl_xor(acc[j], 32);
    }

    if (s == 0) {
        const float di = dinv[node];
        const short8 xs = *(const short8*)(xd + (long)node * 128 + c * 8);
        unsigned short o[8];
#pragma unroll
        for (int j = 0; j < 8; ++j)
            o[j] = f2bf(di * (acc[j] + bf2f((unsigned short)xs[j])));
        *(uint4*)(gx + (long)node * 256 + c * 8) = *(uint4*)o;
    }
}

// ---------------------------------------------------------------------------
// out[N,128] = bf16_gemm( gx[N,256], Wab[256,128] ) + bv
// 4 waves/block, each wave: 16 rows x 128 cols via 8 accumulators of 16x16x32.
__global__ __launch_bounds__(256) void k_mm(const unsigned short* __restrict__ gx,
                                            const unsigned short* __restrict__ Wp,
                                            const float* __restrict__ bv,
                                            float* __restrict__ out) {
    const int tid = threadIdx.x;
    const int wave = tid >> 6;
    const int lane = tid & 63;
    const int quad = lane >> 4;
    const int lr = lane & 15;
    const int row0 = blockIdx.x * 64 + wave * 16;

    int ar = row0 + lr;
    if (ar >= N_NODES) ar = N_NODES - 1;  // clamp loads; stores are guarded
    const unsigned short* aptr = gx + (long)ar * 256 + quad * 8;

    f32x4 acc[8] = {};

#pragma unroll
    for (int s = 0; s < 8; ++s) {
        const short8 a = *(const short8*)(aptr + s * 32);
#pragma unroll
        for (int t = 0; t < 8; ++t) {
            const short8 b = *(const short8*)(Wp + ((long)(s * 8 + t) * 64 + lane) * 8);
            acc[t] = __builtin_amdgcn_mfma_f32_16x16x32_bf16(a, b, acc[t], 0, 0, 0);
        }
    }

#pragma unroll
    for (int t = 0; t < 8; ++t) {
        const int col = t * 16 + lr;
        const float bvv = bv[col];
#pragma unroll
        for (int r = 0; r < 4; ++r) {
            const int row = row0 + quad * 4 + r;
            if (row < N_NODES) out[(long)row * D + col] = acc[t][r] + bvv;
        }
    }
}

// ---------------------------------------------------------------------------
extern "C" void kernel_launch(void* const* d_in, const int* in_sizes, int n_in,
                              void* d_out, int out_size, void* d_ws, size_t ws_size,
                              hipStream_t stream) {
    const float* x  = (const float*)d_in[0];
    const int*   ei = (const int*)d_in[1];  // [2, E] flat: row0=src, row1=dst
    const float* Wc = (const float*)d_in[2];
    const float* bc = (const float*)d_in[3];
    const float* W0 = (const float*)d_in[4];
    const float* Wt = (const float*)d_in[5];
    float* out = (float*)d_out;

    const int* src = ei;
    const int* dst = ei + N_EDGES;

    // workspace layout:
    //   xd bf16 [N*128] | gx bf16 [N*256] | cnt [N] | row_start [N] | dinv [N] |
    //   esrc [NB*CAPB] | pbuf [NB*CAPB] | bv f32 [D] | Wp bf16 [256*128] | gcur [NB]
    unsigned short* xd = (unsigned short*)d_ws;
    unsigned short* gx = xd + (size_t)N_NODES * 128;
    int*   cnt        = (int*)(gx + (size_t)N_NODES * 256);
    int*   row_start  = cnt + N_NODES;
    float* dinv       = (float*)(row_start + N_NODES);
    int*   esrc       = (int*)(dinv + N_NODES);
    unsigned int* pbuf = (unsigned int*)(esrc + (size_t)NB * CAPB);
    float* bv         = (float*)(pbuf + (size_t)NB * CAPB);
    unsigned short* Wp = (unsigned short*)(bv + D);
    int*   gcur       = (int*)(Wp + 256 * D);

    k_init<<<1, 256, 0, stream>>>(gcur);
    k_part1<<<P1_BLOCKS + 17, 256, 0, stream>>>(src, dst, gcur, pbuf,
                                                Wc, W0, Wt, bc, Wp, bv);
    k_part2<<<NB, 256, 0, stream>>>(pbuf, gcur, row_start, cnt, dinv, esrc,
                                    x, xd, gx);
    k_gather<<<N_NODES / 4, 256, 0, stream>>>(xd, row_start, cnt, esrc, dinv, gx);
    k_mm<<<(N_NODES + 63) / 64, 256, 0, stream>>>(gx, Wp, bv, out);
}

// Round 11
// 178.995 us; speedup vs baseline: 1.0433x; 1.0433x over previous
//
#include <hip/hip_runtime.h>

#define N_NODES 50000
#define N_EDGES 800000
#define D 128
#define NB 196                 // buckets: bucket = dst >> 8, 256 nodes each
#define CAPB 8192              // fixed slots per bucket (mean 4082, ~64 sigma)
#define P1_BLOCKS 256
#define EPB ((N_EDGES + P1_BLOCKS - 1) / P1_BLOCKS)  // 3125 edges/block
#define CAP 64                 // LDS staging slots per bucket in part1

typedef __attribute__((ext_vector_type(8))) short short8;
typedef __attribute__((ext_vector_type(4))) float f32x4;

// round-to-nearest-even f32 -> bf16 (as ushort)
__device__ __forceinline__ unsigned short f2bf(float f) {
    unsigned int u = __builtin_bit_cast(unsigned int, f);
    u += 0x7FFFu + ((u >> 16) & 1u);
    return (unsigned short)(u >> 16);
}
__device__ __forceinline__ float bf2f(unsigned short h) {
    unsigned int u = ((unsigned int)h) << 16;
    return __builtin_bit_cast(float, u);
}

// ---------------------------------------------------------------------------
// gcur[b] = b * CAPB   (fixed bucket bases; no hist/scan/memset needed)
__global__ void k_init(int* __restrict__ gcur) {
    const int t = threadIdx.x;
    if (t < NB) gcur[t] = t * CAPB;
}

// Partition edges into fixed-base buckets with LDS write-combining.
// pbuf code: (local_dst << 16) | src   (src < 65536, local_dst < 256)
__global__ __launch_bounds__(256) void k_part1(const int* __restrict__ src,
                                               const int* __restrict__ dst,
                                               int* __restrict__ gcur,
                                               unsigned int* __restrict__ pbuf) {
    __shared__ unsigned int stage[NB][CAP + 1];  // +1 pad: drain reads conflict-free
    __shared__ int scnt[NB];
    const int t = threadIdx.x;
    for (int i = t; i < NB; i += 256) scnt[i] = 0;
    __syncthreads();

    const long e0 = (long)blockIdx.x * EPB;
    const long e1 = (e0 + EPB < N_EDGES) ? e0 + EPB : N_EDGES;
    for (long e = e0 + t; e < e1; e += 256) {
        const int s = src[e];
        const int d = dst[e];
        const int b = d >> 8;
        const unsigned int p = ((unsigned int)(d & 255) << 16) | (unsigned int)s;
        const int slot = atomicAdd(&scnt[b], 1);
        if (slot < CAP) {
            stage[b][slot] = p;
        } else {  // spill (statistically ~never; correctness for any distribution)
            const int pos = atomicAdd(&gcur[b], 1);
            pbuf[pos] = p;
        }
    }
    __syncthreads();
    // cooperative drain: thread t drains bucket t in one contiguous burst
    if (t < NB) {
        const int n = (scnt[t] < CAP) ? scnt[t] : CAP;
        if (n > 0) {
            const int pos = atomicAdd(&gcur[t], n);
            for (int i = 0; i < n; ++i) pbuf[pos + i] = stage[t][i];
        }
    }
}

// Per-bucket local CSR build: hist + scan in LDS, scatter into L2-local window.
// Produces row_start / cnt / dinv / dsq (= sqrt(deg), for k_mm's epilogue).
__global__ __launch_bounds__(256) void k_part2(const unsigned int* __restrict__ pbuf,
                                               const int* __restrict__ gcur,
                                               int* __restrict__ row_start,
                                               int* __restrict__ cnt,
                                               float* __restrict__ dinv,
                                               float* __restrict__ dsq,
                                               int* __restrict__ esrc) {
    __shared__ int lcnt[256];
    __shared__ int lcur[256];
    __shared__ int stmp[256];
    const int b = blockIdx.x;
    const int t = threadIdx.x;
    const int base = b * CAPB;
    const int n = gcur[b] - base;

    lcnt[t] = 0;
    __syncthreads();
    for (int i = t; i < n; i += 256) atomicAdd(&lcnt[pbuf[base + i] >> 16], 1);
    __syncthreads();

    const int c = lcnt[t];
    stmp[t] = c;
    __syncthreads();
    for (int off = 1; off < 256; off <<= 1) {
        int u = (t >= off) ? stmp[t - off] : 0;
        __syncthreads();
        stmp[t] += u;
        __syncthreads();
    }
    const int ls = base + stmp[t] - c;  // exclusive, within bucket window
    lcur[t] = ls;
    const int node = b * 256 + t;
    if (node < N_NODES) {
        row_start[node] = ls;
        cnt[node] = c;
        const float deg = (float)c + 1.0f;
        dinv[node] = rsqrtf(deg);
        dsq[node] = sqrtf(deg);
    }
    __syncthreads();

    for (int i = t; i < n; i += 256) {
        const unsigned int p = pbuf[base + i];
        const int pos = atomicAdd(&lcur[p >> 16], 1);
        esrc[pos] = (int)(p & 0xFFFFu);
    }
}

// ---------------------------------------------------------------------------
// Fused weight-pack + x-cast.
// Blocks 0..15: pack Wab = [Wc + Wc@Wt ; W0 - Wt] (256x128) into bf16 B-fragment
// order for 16x16x32. Block 16: bv = bc + bc@Wt.
// Blocks 17..: xd[n] = bf16(dinv[n]*x[n])   (x-half of A recovered as dsq*xd).
__global__ __launch_bounds__(256) void k_wx(const float* __restrict__ Wc,
                                            const float* __restrict__ W0,
                                            const float* __restrict__ Wt,
                                            const float* __restrict__ bc,
                                            const float* __restrict__ x,
                                            const float* __restrict__ dinv,
                                            unsigned short* __restrict__ Wp,
                                            float* __restrict__ bv,
                                            unsigned short* __restrict__ xd) {
    __shared__ float sWt[D * D];
    const int t = threadIdx.x;

    if (blockIdx.x < 17) {
        for (int i = t * 4; i < D * D; i += 256 * 4)
            *(float4*)(sWt + i) = *(const float4*)(Wt + i);
        __syncthreads();

        if (blockIdx.x == 16) {
            if (t < D) {
                float acc = bc[t];
#pragma unroll 16
                for (int k = 0; k < D; ++k) acc += bc[k] * sWt[k * D + t];
                bv[t] = acc;
            }
            return;
        }
        const int id = blockIdx.x * 256 + t;  // 0..4095
        const int lane = id & 63;
        const int tile = (id >> 6) & 7;
        const int step = id >> 9;
        const int n = tile * 16 + (lane & 15);
        const int kbase = step * 32 + (lane >> 4) * 8;
        unsigned short v[8];
#pragma unroll
        for (int j = 0; j < 8; ++j) {
            const int k = kbase + j;
            float f;
            if (k < D) {
                f = Wc[k * D + n];
#pragma unroll 16
                for (int m = 0; m < D; ++m) f += Wc[k * D + m] * sWt[m * D + n];
            } else {
                f = W0[(k - D) * D + n] - sWt[(k - D) * D + n];
            }
            v[j] = f2bf(f);
        }
        *(uint4*)(Wp + (long)id * 8) = *(uint4*)v;
        return;
    }

    // xcast path
    const int gid = (blockIdx.x - 17) * 256 + t;  // 0 .. N*16-1
    const int node = gid >> 4;
    const int c = gid & 15;
    const float di = dinv[node];
    const float4 a = ((const float4*)x)[(long)node * 32 + c * 2];
    const float4 b = ((const float4*)x)[(long)node * 32 + c * 2 + 1];
    const float f[8] = {a.x, a.y, a.z, a.w, b.x, b.y, b.z, b.w};
    unsigned short vd[8];
#pragma unroll
    for (int j = 0; j < 8; ++j) vd[j] = f2bf(di * f[j]);
    *(uint4*)(xd + (long)node * 128 + c * 8) = *(uint4*)vd;
}

// ---------------------------------------------------------------------------
// Gather (bf16 rows): one 64-lane wave per node (4 nodes / block, 12500 blocks).
//   g[n] = dinv[n] * ( sum_e xd[src_e] + xd[n] )      (xd pre-scaled by dinv)
// Lane layout: c = lane&15 -> 8-elem chunk (16 B), s = lane>>4 -> edge slot 0..3.
// Unroll 4 per slot: 16 outstanding 16 B loads per wave. Writes compact g[N,128].
__global__ __launch_bounds__(256) void k_gather(const unsigned short* __restrict__ xd,
                                                const int* __restrict__ row_start,
                                                const int* __restrict__ cnt,
                                                const int* __restrict__ esrc,
                                                const float* __restrict__ dinv,
                                                unsigned short* __restrict__ g) {
    const int node = blockIdx.x * 4 + (threadIdx.x >> 6);
    const int lane = threadIdx.x & 63;
    const int c = lane & 15;
    const int s = lane >> 4;
    const int begin = row_start[node];
    const int end = begin + cnt[node];

    float acc[8] = {};
    int i = begin + s;
    for (; i + 12 < end; i += 16) {  // four edges in flight per slot
        const int a0 = esrc[i];
        const int a1 = esrc[i + 4];
        const int a2 = esrc[i + 8];
        const int a3 = esrc[i + 12];
        const short8 v0 = *(const short8*)(xd + (long)a0 * 128 + c * 8);
        const short8 v1 = *(const short8*)(xd + (long)a1 * 128 + c * 8);
        const short8 v2 = *(const short8*)(xd + (long)a2 * 128 + c * 8);
        const short8 v3 = *(const short8*)(xd + (long)a3 * 128 + c * 8);
#pragma unroll
        for (int j = 0; j < 8; ++j)
            acc[j] += (bf2f((unsigned short)v0[j]) + bf2f((unsigned short)v1[j])) +
                      (bf2f((unsigned short)v2[j]) + bf2f((unsigned short)v3[j]));
    }
    for (; i < end; i += 4) {
        const int a0 = esrc[i];
        const short8 v0 = *(const short8*)(xd + (long)a0 * 128 + c * 8);
#pragma unroll
        for (int j = 0; j < 8; ++j) acc[j] += bf2f((unsigned short)v0[j]);
    }

#pragma unroll
    for (int j = 0; j < 8; ++j) {
        acc[j] += __shfl_xor(acc[j], 16);
        acc[j] += __shfl_xor(acc[j], 32);
    }

    if (s == 0) {
        const float di = dinv[node];
        const short8 xs = *(const short8*)(xd + (long)node * 128 + c * 8);
        unsigned short o[8];
#pragma unroll
        for (int j = 0; j < 8; ++j)
            o[j] = f2bf(di * (acc[j] + bf2f((unsigned short)xs[j])));
        *(uint4*)(g + (long)node * 128 + c * 8) = *(uint4*)o;
    }
}

// ---------------------------------------------------------------------------
// out = g@Wa + diag(dsq)·(xd@Wb) + bv    (A halves from g and xd; two acc banks)
// 4 waves/block, each wave: 16 rows x 128 cols via 16x16x32 MFMA.
__global__ __launch_bounds__(256) void k_mm(const unsigned short* __restrict__ g,
                                            const unsigned short* __restrict__ xd,
                                            const unsigned short* __restrict__ Wp,
                                            const float* __restrict__ bv,
                                            const float* __restrict__ dsq,
                                            float* __restrict__ out) {
    const int tid = threadIdx.x;
    const int wave = tid >> 6;
    const int lane = tid & 63;
    const int quad = lane >> 4;
    const int lr = lane & 15;
    const int row0 = blockIdx.x * 64 + wave * 16;

    int ar = row0 + lr;
    if (ar >= N_NODES) ar = N_NODES - 1;  // clamp loads; stores are guarded

    f32x4 accA[8] = {};  // g @ Wa   (Wp rows 0..127)
    f32x4 accB[8] = {};  // xd @ Wb  (Wp rows 128..255), scaled by dsq in epilogue

#pragma unroll
    for (int s = 0; s < 4; ++s) {
        const short8 a = *(const short8*)(g + (long)ar * 128 + s * 32 + quad * 8);
#pragma unroll
        for (int t = 0; t < 8; ++t) {
            const short8 b = *(const short8*)(Wp + ((long)(s * 8 + t) * 64 + lane) * 8);
            accA[t] = __builtin_amdgcn_mfma_f32_16x16x32_bf16(a, b, accA[t], 0, 0, 0);
        }
    }
#pragma unroll
    for (int s = 4; s < 8; ++s) {
        const short8 a = *(const short8*)(xd + (long)ar * 128 + (s - 4) * 32 + quad * 8);
#pragma unroll
        for (int t = 0; t < 8; ++t) {
            const short8 b = *(const short8*)(Wp + ((long)(s * 8 + t) * 64 + lane) * 8);
            accB[t] = __builtin_amdgcn_mfma_f32_16x16x32_bf16(a, b, accB[t], 0, 0, 0);
        }
    }

    float sq[4];
#pragma unroll
    for (int r = 0; r < 4; ++r) {
        const int row = row0 + quad * 4 + r;
        sq[r] = (row < N_NODES) ? dsq[row] : 0.0f;
    }

#pragma unroll
    for (int t = 0; t < 8; ++t) {
        const int col = t * 16 + lr;
        const float bvv = bv[col];
#pragma unroll
        for (int r = 0; r < 4; ++r) {
            const int row = row0 + quad * 4 + r;
            if (row < N_NODES)
                out[(long)row * D + col] = accA[t][r] + sq[r] * accB[t][r] + bvv;
        }
    }
}

// ---------------------------------------------------------------------------
extern "C" void kernel_launch(void* const* d_in, const int* in_sizes, int n_in,
                              void* d_out, int out_size, void* d_ws, size_t ws_size,
                              hipStream_t stream) {
    const float* x  = (const float*)d_in[0];
    const int*   ei = (const int*)d_in[1];  // [2, E] flat: row0=src, row1=dst
    const float* Wc = (const float*)d_in[2];
    const float* bc = (const float*)d_in[3];
    const float* W0 = (const float*)d_in[4];
    const float* Wt = (const float*)d_in[5];
    float* out = (float*)d_out;

    const int* src = ei;
    const int* dst = ei + N_EDGES;

    // workspace layout:
    //   xd bf16 [N*128] | g bf16 [N*128] | cnt [N] | row_start [N] | dinv [N] |
    //   dsq [N] | esrc [NB*CAPB] | pbuf [NB*CAPB] | bv f32 [D] |
    //   Wp bf16 [256*128] | gcur [NB]
    unsigned short* xd = (unsigned short*)d_ws;
    unsigned short* g  = xd + (size_t)N_NODES * 128;
    int*   cnt        = (int*)(g + (size_t)N_NODES * 128);
    int*   row_start  = cnt + N_NODES;
    float* dinv       = (float*)(row_start + N_NODES);
    float* dsq        = dinv + N_NODES;
    int*   esrc       = (int*)(dsq + N_NODES);
    unsigned int* pbuf = (unsigned int*)(esrc + (size_t)NB * CAPB);
    float* bv         = (float*)(pbuf + (size_t)NB * CAPB);
    unsigned short* Wp = (unsigned short*)(bv + D);
    int*   gcur       = (int*)(Wp + 256 * D);

    k_init<<<1, 256, 0, stream>>>(gcur);
    k_part1<<<P1_BLOCKS, 256, 0, stream>>>(src, dst, gcur, pbuf);
    k_part2<<<NB, 256, 0, stream>>>(pbuf, gcur, row_start, cnt, dinv, dsq, esrc);
    k_wx<<<17 + (N_NODES * 16) / 256, 256, 0, stream>>>(Wc, W0, Wt, bc, x, dinv,
                                                        Wp, bv, xd);
    k_gather<<<N_NODES / 4, 256, 0, stream>>>(xd, row_start, cnt, esrc, dinv, g);
    k_mm<<<(N_NODES + 63) / 64, 256, 0, stream>>>(g, xd, Wp, bv, dsq, out);
}